// Round 18
// baseline (135.281 us; speedup 1.0000x reference)
//
#include <hip/hip_runtime.h>

// LocalRefinedAttention round 18 = round 13 with barrier-free middle section.
// Round 17 post-mortem: setprio neutral (barrier-synced regime, m190-null).
// The 4 per-patch Bu barriers exist ONLY because O overwrites Xs[u] in place
// (WAR hazard). Fix: separate Os[] LDS buffer -> Xs is read-only after
// staging, O writes are per-wave-disjoint rows -> the whole proj+attn middle
// (~80% of work) runs with ZERO inter-wave sync; barriers 6 -> 2 (B0, Bf).
// PBLK 4->3 so Xs(24KB)+Os(24KB)=48KB keeps 3 blocks/CU (= r13's measured
// residency). Grid 3072 (div by 8); 48%3==0 so 3-patch groups stay in-row.
//
// B=4, C=64, H=W=192, PS=8, STRIDE=4, PAD=2, NHEADS=4, head_dim=16.
// token t = channel; feature/spatial s = pi*8+pj; h = 4*ib+pi-2, w = 4*jb+pj-2.
// Parity planes: p = (pi>=4)*2 + (pj>=4); plane[p][b][ch][h][w2=196] at w2=w+2.
// Each (pixel, p) has exactly one writing patch -> no atomics, no memset.

typedef _Float16 f16;
typedef _Float16 f16x2 __attribute__((ext_vector_type(2)));
typedef _Float16 f16x4 __attribute__((ext_vector_type(4)));
typedef _Float16 f16x8 __attribute__((ext_vector_type(8)));
typedef float    f32x4 __attribute__((ext_vector_type(4)));

#define NHP 48
#define LPB (NHP * NHP)          // 2304
#define NPATCH (4 * LPB)         // 9216
#define PBLK 3                   // patches per block (same ib, jb0..jb0+2)
#define NBLK (NPATCH / PBLK)     // 3072 blocks (div by 8)
#define NXP 8                    // float2 pairs per row in the 3-patch union
#define PLELEM (256 * 192 * 196) // f16 elements per parity plane
#define WS_NEED (32768ull + 4ull * PLELEM * 2ull)

#define MFMA32(A, B, C) __builtin_amdgcn_mfma_f32_16x16x32_f16((A), (B), (C), 0, 0, 0)
#define MFMA16(A, B, C) __builtin_amdgcn_mfma_f32_16x16x16f16((A), (B), (C), 0, 0, 0)

// XOR-swizzled LDS index: token-major pitch 64 f16; flips f16-index bits 3..5
// by (tok&7). Same swizzle on write and read sides.
static __device__ __forceinline__ int XS(int tok, int f) {
    return tok * 64 + (f ^ ((tok & 7) << 3));
}

static __device__ __forceinline__ f16x4 pack4(f32x4 a) {
    f16x4 r;
    r[0] = (f16)a[0]; r[1] = (f16)a[1]; r[2] = (f16)a[2]; r[3] = (f16)a[3];
    return r;
}

// ---- weights fp32 -> f16 row-major; SCALE*log2(e) folded into Wq ----
__global__ __launch_bounds__(256) void wcvt_kernel(
    const float* __restrict__ wq, const float* __restrict__ wk,
    const float* __restrict__ wv, const float* __restrict__ wp,
    f16* __restrict__ wh)
{
    const int idx = blockIdx.x * 256 + threadIdx.x;   // 0..16383
    const int m = idx >> 12;
    const int r = idx & 4095;
    const float* src = (m == 0) ? wq : (m == 1) ? wk : (m == 2) ? wv : wp;
    const float s = (m == 0) ? 0.36067376022224085f : 1.0f;  // 0.25 * log2(e)
    wh[idx] = (f16)(src[r] * s);
}

template <bool USE_PLANES>
__global__ __launch_bounds__(256, 4) void patch_attn_kernel(
    const float* __restrict__ x, const f16* __restrict__ wh,
    f16* __restrict__ planes, float* __restrict__ out)
{
    // Xs: X tokens (swizzled pitch 64), READ-ONLY after B0.
    // Os: attention output, per-wave-disjoint row writes -> no WAR barriers.
    __shared__ f16 Xs[PBLK][64 * 64];   // 24 KB
    __shared__ f16 Os[PBLK][64 * 64];   // 24 KB

    const int tid  = threadIdx.x;
    const int wv_  = tid >> 6;
    const int lane = tid & 63;
    const int lr   = lane & 15;
    const int lg   = lane >> 4;
    const int chL  = wv_ * 16 + lr;          // this thread's token/channel row

    // XCD-bijective swizzle; consecutive same-XCD blocks = consecutive
    // 3-patch groups (HW dispatch order -> jb-adjacent concurrent blocks).
    const int n    = blockIdx.x;
    const int qb   = (n & 7) * (NBLK / 8) + (n >> 3);
    const int pid0 = qb * PBLK;
    const int b    = pid0 / LPB;
    const int rem  = pid0 - b * LPB;
    const int ib   = rem / NHP;
    const int jb0  = rem - ib * NHP;         // block patches: jb0..jb0+2
    const int r0   = ib * 4 - 2;             // shared rows (same ib for all 3)
    const int c00  = jb0 * 4 - 2;            // patch u starts at c00 + 4u

    const f32x4 Z = (f32x4){0.f, 0.f, 0.f, 0.f};

    // ======== X global loads (deduped across the 3 patches) ========
    // Union per row = floats c00 .. c00+15 = 8 aligned float2 pairs;
    // patch u uses pairs 2u..2u+3.
    float2 xr[2][NXP];
    {
        const float* xb = x + ((size_t)(b * 64 + chL) * 192) * 192;
        #pragma unroll
        for (int kt = 0; kt < 2; ++kt) {
            const int rr = r0 + kt * 4 + lg;
            const int rc = (rr >= 0 && rr < 192) ? rr : 0;
            const float* src = xb + (size_t)rc * 192;
            #pragma unroll
            for (int j = 0; j < NXP; ++j) {
                int cc = c00 + 2 * j;
                cc = (cc < 0) ? 0 : ((cc > 190) ? 190 : cc);
                xr[kt][j] = *(const float2*)(src + cc);
            }
        }
    }

    // ---- convert once with shared masks ----
    f16x2 ht[2][NXP];
    #pragma unroll
    for (int kt = 0; kt < 2; ++kt) {
        const int rr = r0 + kt * 4 + lg;
        const bool rko = (rr >= 0) && (rr < 192);
        #pragma unroll
        for (int j = 0; j < NXP; ++j) {
            const int cc = c00 + 2 * j;
            const bool ok = rko && (cc >= 0) && (cc <= 190);
            ht[kt][j][0] = ok ? (f16)xr[kt][j].x : (f16)0.f;
            ht[kt][j][1] = ok ? (f16)xr[kt][j].y : (f16)0.f;
        }
    }

    // ---- stage X to LDS (swizzled) ----
    #pragma unroll
    for (int u = 0; u < PBLK; ++u)
        #pragma unroll
        for (int kt = 0; kt < 2; ++kt) {
            f16x8 v;
            #pragma unroll
            for (int j = 0; j < 4; ++j) {
                v[2 * j]     = ht[kt][2 * u + j][0];
                v[2 * j + 1] = ht[kt][2 * u + j][1];
            }
            *(f16x8*)&Xs[u][XS(chL, kt * 32 + lg * 8)] = v;
        }
    __syncthreads();   // B0: X staged; Xs is read-only from here on

    // ======== wave = head h: own-head weight fragments (once) ========
    const int h = wv_;
    const int wrow = (h * 16 + lr) * 64 + lg * 8;
    const f16x8 wqA0 = *(const f16x8*)&wh[wrow];
    const f16x8 wqA1 = *(const f16x8*)&wh[wrow + 32];
    const f16x8 wkA0 = *(const f16x8*)&wh[4096 + wrow];
    const f16x8 wkA1 = *(const f16x8*)&wh[4096 + wrow + 32];
    const f16x8 wvB0 = *(const f16x8*)&wh[8192 + wrow];
    const f16x8 wvB1 = *(const f16x8*)&wh[8192 + wrow + 32];

    // ======== barrier-free middle: per patch, proj -> attention -> Os[u] ====
    #pragma unroll
    for (int u = 0; u < PBLK; ++u) {
        // Q^T/K^T/V C-frags for all 4 token tiles (round-2-verified chains).
        f16x4 Qf[4], Kf[4], Vf[4];
        #pragma unroll
        for (int tt = 0; tt < 4; ++tt) {
            const int tok = tt * 16 + lr;
            const f16x8 xb0 = *(const f16x8*)&Xs[u][XS(tok, lg * 8)];
            const f16x8 xb1 = *(const f16x8*)&Xs[u][XS(tok, 32 + lg * 8)];
            f32x4 aq = MFMA32(wqA0, xb0, Z);
            aq = MFMA32(wqA1, xb1, aq);
            Qf[tt] = pack4(aq);                 // Q^T[d][tok=lr] (scaled, log2)
            f32x4 ak = MFMA32(wkA0, xb0, Z);
            ak = MFMA32(wkA1, xb1, ak);
            Kf[tt] = pack4(ak);                 // K^T C-frag == A-frag(K)
            f32x4 av = MFMA32(xb0, wvB0, Z);
            av = MFMA32(xb1, wvB1, av);
            Vf[tt] = pack4(av);                 // V C-frag == A-frag(V^T)
        }

        #pragma unroll
        for (int tj = 0; tj < 4; ++tj) {
            // S^T[key=ti*16+lg*4+rg][q=tj*16+lr] (log2 domain)
            f32x4 s[4];
            #pragma unroll
            for (int ti = 0; ti < 4; ++ti)
                s[ti] = MFMA16(Kf[ti], Qf[tj], Z);

            // No max subtraction (r13-verified): exp2 directly off MFMA output.
            f16x4 pf[4];            // unnormalized P^T[key][q] as B-frags
            float ps[4];            // per-ti partial sums (tree)
            #pragma unroll
            for (int ti = 0; ti < 4; ++ti) {
                float e0 = __builtin_amdgcn_exp2f(s[ti][0]);
                float e1 = __builtin_amdgcn_exp2f(s[ti][1]);
                float e2 = __builtin_amdgcn_exp2f(s[ti][2]);
                float e3 = __builtin_amdgcn_exp2f(s[ti][3]);
                pf[ti][0] = (f16)e0;
                pf[ti][1] = (f16)e1;
                pf[ti][2] = (f16)e2;
                pf[ti][3] = (f16)e3;
                ps[ti] = (e0 + e1) + (e2 + e3);
            }
            float sum = (ps[0] + ps[1]) + (ps[2] + ps[3]);
            sum += __shfl_xor(sum, 16, 64);
            sum += __shfl_xor(sum, 32, 64);

            // PV MFMAs don't need sum -> overlap with the shfl reduce + rcp.
            f32x4 o = Z;
            #pragma unroll
            for (int ti = 0; ti < 4; ++ti)
                o = MFMA16(Vf[ti], pf[ti], o);  // O^T[d][q=tj*16+lr] unnormalized

            const float rs = __builtin_amdgcn_rcpf(sum);
            o[0] *= rs; o[1] *= rs; o[2] *= rs; o[3] *= rs;

            // write to Os (wave-disjoint d-rows) -> no WAR vs Xs reads
            *(f16x4*)&Os[u][XS(tj * 16 + lr, h * 16 + lg * 4)] = pack4(o);
        }
    }
    __syncthreads();   // Bf: all O writes visible

    // ======== Phase 4: Y^T = Wp * O^T ; OB hoisted, ct-outer stores ========
    const f16* whp = wh + 3 * 4096;
    f16x4 wa[4][4];
    #pragma unroll
    for (int ct = 0; ct < 4; ++ct)
        #pragma unroll
        for (int dt = 0; dt < 4; ++dt)
            wa[ct][dt] = *(const f16x4*)&whp[(ct * 16 + lr) * 64 + dt * 16 + lg * 4];

    f16x4 OB[PBLK][4];   // O^T B-frags for the wave's own channel row, all u
    #pragma unroll
    for (int u = 0; u < PBLK; ++u)
        #pragma unroll
        for (int dt = 0; dt < 4; ++dt)
            OB[u][dt] = *(const f16x4*)&Os[u][XS(chL, dt * 16 + lg * 4)];

    const int ch = b * 64 + chL;             // output channel (with batch)
    #pragma unroll
    for (int ct = 0; ct < 4; ++ct) {
        const int pi  = ct * 2 + (lg >> 1);  // cs=ct*16+lg*4+rg -> pi, pj=(lg&1)*4+rg
        const int pjh = lg & 1;
        const int hh  = r0 + pi;             // shared by all 3 patches (same ib)

        #pragma unroll
        for (int u = 0; u < PBLK; ++u) {
            f32x4 y = Z;
            #pragma unroll
            for (int dt = 0; dt < 4; ++dt)
                y = MFMA16(wa[ct][dt], OB[u][dt], y);
            // lane holds Y^T[cs=ct*16+lg*4+rg][tok=lr -> channel chL];
            // consecutive u at same ct -> adjacent 8B runs complete plane lines.
            if (USE_PLANES) {
                if (hh >= 0 && hh < 192) {
                    const int p = (pi >> 2) * 2 + pjh;
                    const size_t off = ((size_t)ch * 192 + hh) * 196 + 4 * (jb0 + u + pjh);
                    *(f16x4*)(planes + (size_t)p * PLELEM + off) = pack4(y);
                }
            } else {
                if (hh >= 0 && hh < 192) {
                    const float chc = (hh >= 2 && hh <= 189) ? 2.f : 1.f;
                    float* op = out + ((size_t)ch * 192 + hh) * 192;
                    const int c0u = c00 + 4 * u;
                    #pragma unroll
                    for (int rg = 0; rg < 4; ++rg) {
                        const int ww = c0u + pjh * 4 + rg;
                        if (ww >= 0 && ww < 192) {
                            const float cwc = (ww >= 2 && ww <= 189) ? 2.f : 1.f;
                            atomicAdd(op + ww, y[rg] / (chc * cwc + 1e-6f));
                        }
                    }
                }
            }
        }
    }
}

// ---- Pass B: dense coalesced fold of the 4 parity planes ----
__global__ __launch_bounds__(256) void fold_kernel(
    const f16* __restrict__ planes, float* __restrict__ out)
{
    const int idx = blockIdx.x * 256 + threadIdx.x;   // 0..9437183
    const int w  = idx % 192;
    const int t  = idx / 192;
    const int h  = t % 192;
    const int bc = t / 192;
    const bool vlh = (h <= 189), vhh = (h >= 2);
    const bool vlw = (w <= 189), vhw = (w >= 2);
    const size_t base = ((size_t)bc * 192 + h) * 196 + (w + 2);
    float s = 0.f;
    if (vlh && vlw) s += (float)planes[0 * (size_t)PLELEM + base];
    if (vlh && vhw) s += (float)planes[1 * (size_t)PLELEM + base];
    if (vhh && vlw) s += (float)planes[2 * (size_t)PLELEM + base];
    if (vhh && vhw) s += (float)planes[3 * (size_t)PLELEM + base];
    const float cnt = (float)(((int)vlh + (int)vhh) * ((int)vlw + (int)vhw));
    out[idx] = s / (cnt + 1e-6f);
}

extern "C" void kernel_launch(void* const* d_in, const int* in_sizes, int n_in,
                              void* d_out, int out_size, void* d_ws, size_t ws_size,
                              hipStream_t stream)
{
    const float* x  = (const float*)d_in[0];
    const float* wq = (const float*)d_in[1];
    const float* wk = (const float*)d_in[2];
    const float* wv = (const float*)d_in[3];
    const float* wp = (const float*)d_in[4];
    float* out = (float*)d_out;
    f16* wh = (f16*)d_ws;

    wcvt_kernel<<<64, 256, 0, stream>>>(wq, wk, wv, wp, wh);

    if (ws_size >= WS_NEED) {
        f16* planes = (f16*)((char*)d_ws + 32768);
        patch_attn_kernel<true><<<NBLK, 256, 0, stream>>>(x, wh, planes, out);
        fold_kernel<<<36864, 256, 0, stream>>>(planes, out);
    } else {
        hipMemsetAsync(d_out, 0, (size_t)out_size * sizeof(float), stream);
        patch_attn_kernel<false><<<NBLK, 256, 0, stream>>>(x, wh, nullptr, out);
    }
}

// Round 19
// 111.373 us; speedup vs baseline: 1.2147x; 1.2147x over previous
//
#include <hip/hip_runtime.h>

// LocalRefinedAttention round 19 = round 13 patch kernel (best measured:
// 127.4us total, patch ~99us) + 4-wide vectorized fold pass.
// Round 14-18 post-mortem: six structural probes around r13 (pair-barriers,
// PBLK=2, 8-wave splits x2, setprio, barrier-free Os) all regress or tie ->
// r13 is the converged patch design (productive-issue floor ~42us; remaining
// gap is distributed latency immune to TLP/ILP/priority/barrier topology).
// This round reverts the patch kernel to r13 verbatim and vectorizes the only
// untouched dispatch: fold does 16x 2B loads + 4 stores per 4 outputs ->
// 8x f16x2 loads + 1 float4 store (base = 2 mod 4 elems -> 4B-aligned).
//
// B=4, C=64, H=W=192, PS=8, STRIDE=4, PAD=2, NHEADS=4, head_dim=16.
// token t = channel; feature/spatial s = pi*8+pj; h = 4*ib+pi-2, w = 4*jb+pj-2.
// Parity planes: p = (pi>=4)*2 + (pj>=4); plane[p][b][ch][h][w2=196] at w2=w+2.
// Each (pixel, p) has exactly one writing patch -> no atomics, no memset.

typedef _Float16 f16;
typedef _Float16 f16x2 __attribute__((ext_vector_type(2)));
typedef _Float16 f16x4 __attribute__((ext_vector_type(4)));
typedef _Float16 f16x8 __attribute__((ext_vector_type(8)));
typedef float    f32x4 __attribute__((ext_vector_type(4)));

#define NHP 48
#define LPB (NHP * NHP)          // 2304
#define NPATCH (4 * LPB)         // 9216
#define PBLK 4                   // patches per block (same ib, jb0..jb0+3)
#define NBLK (NPATCH / PBLK)     // 2304 blocks
#define PLELEM (256 * 192 * 196) // f16 elements per parity plane
#define WS_NEED (32768ull + 4ull * PLELEM * 2ull)

#define MFMA32(A, B, C) __builtin_amdgcn_mfma_f32_16x16x32_f16((A), (B), (C), 0, 0, 0)
#define MFMA16(A, B, C) __builtin_amdgcn_mfma_f32_16x16x16f16((A), (B), (C), 0, 0, 0)

// XOR-swizzled LDS index: token-major pitch 64 f16; flips f16-index bits 3..5
// by (tok&7). Same swizzle on write and read sides.
static __device__ __forceinline__ int XS(int tok, int f) {
    return tok * 64 + (f ^ ((tok & 7) << 3));
}

static __device__ __forceinline__ f16x4 pack4(f32x4 a) {
    f16x4 r;
    r[0] = (f16)a[0]; r[1] = (f16)a[1]; r[2] = (f16)a[2]; r[3] = (f16)a[3];
    return r;
}

// ---- weights fp32 -> f16 row-major; SCALE*log2(e) folded into Wq ----
__global__ __launch_bounds__(256) void wcvt_kernel(
    const float* __restrict__ wq, const float* __restrict__ wk,
    const float* __restrict__ wv, const float* __restrict__ wp,
    f16* __restrict__ wh)
{
    const int idx = blockIdx.x * 256 + threadIdx.x;   // 0..16383
    const int m = idx >> 12;
    const int r = idx & 4095;
    const float* src = (m == 0) ? wq : (m == 1) ? wk : (m == 2) ? wv : wp;
    const float s = (m == 0) ? 0.36067376022224085f : 1.0f;  // 0.25 * log2(e)
    wh[idx] = (f16)(src[r] * s);
}

template <bool USE_PLANES>
__global__ __launch_bounds__(256, 4) void patch_attn_kernel(
    const float* __restrict__ x, const f16* __restrict__ wh,
    f16* __restrict__ planes, float* __restrict__ out)
{
    // Xs[u]: X tokens (swizzled pitch 64) -> after per-patch barrier, reused
    // as O. 4 x 64 x 64 x 2B = 32768 B.
    __shared__ f16 Xs[PBLK][64 * 64];

    const int tid  = threadIdx.x;
    const int wv_  = tid >> 6;
    const int lane = tid & 63;
    const int lr   = lane & 15;
    const int lg   = lane >> 4;
    const int chL  = wv_ * 16 + lr;          // this thread's token/channel row

    // XCD-bijective swizzle; consecutive same-XCD blocks = consecutive
    // 4-patch groups (HW dispatch order -> jb-adjacent concurrent blocks).
    const int n    = blockIdx.x;
    const int qb   = (n & 7) * (NBLK / 8) + (n >> 3);
    const int pid0 = qb * PBLK;
    const int b    = pid0 / LPB;
    const int rem  = pid0 - b * LPB;
    const int ib   = rem / NHP;
    const int jb0  = rem - ib * NHP;         // block patches: jb0..jb0+3
    const int r0   = ib * 4 - 2;             // shared rows (same ib for all 4)
    const int c00  = jb0 * 4 - 2;            // patch u starts at c00 + 4u

    const f32x4 Z = (f32x4){0.f, 0.f, 0.f, 0.f};

    // ======== X global loads (deduped across the 4 patches) ========
    float2 xr[2][10];
    {
        const float* xb = x + ((size_t)(b * 64 + chL) * 192) * 192;
        #pragma unroll
        for (int kt = 0; kt < 2; ++kt) {
            const int rr = r0 + kt * 4 + lg;
            const int rc = (rr >= 0 && rr < 192) ? rr : 0;
            const float* src = xb + (size_t)rc * 192;
            #pragma unroll
            for (int j = 0; j < 10; ++j) {
                int cc = c00 + 2 * j;
                cc = (cc < 0) ? 0 : ((cc > 190) ? 190 : cc);
                xr[kt][j] = *(const float2*)(src + cc);
            }
        }
    }

    // ---- convert once with shared masks ----
    f16x2 ht[2][10];
    #pragma unroll
    for (int kt = 0; kt < 2; ++kt) {
        const int rr = r0 + kt * 4 + lg;
        const bool rko = (rr >= 0) && (rr < 192);
        #pragma unroll
        for (int j = 0; j < 10; ++j) {
            const int cc = c00 + 2 * j;
            const bool ok = rko && (cc >= 0) && (cc <= 190);
            ht[kt][j][0] = ok ? (f16)xr[kt][j].x : (f16)0.f;
            ht[kt][j][1] = ok ? (f16)xr[kt][j].y : (f16)0.f;
        }
    }

    // ---- stage X to LDS (swizzled) ----
    #pragma unroll
    for (int u = 0; u < PBLK; ++u)
        #pragma unroll
        for (int kt = 0; kt < 2; ++kt) {
            f16x8 v;
            #pragma unroll
            for (int j = 0; j < 4; ++j) {
                v[2 * j]     = ht[kt][2 * u + j][0];
                v[2 * j + 1] = ht[kt][2 * u + j][1];
            }
            *(f16x8*)&Xs[u][XS(chL, kt * 32 + lg * 8)] = v;
        }
    __syncthreads();   // B0: X staged for all 4 patches

    // ======== wave = head h: own-head weight fragments (once) ========
    const int h = wv_;
    const int wrow = (h * 16 + lr) * 64 + lg * 8;
    const f16x8 wqA0 = *(const f16x8*)&wh[wrow];
    const f16x8 wqA1 = *(const f16x8*)&wh[wrow + 32];
    const f16x8 wkA0 = *(const f16x8*)&wh[4096 + wrow];
    const f16x8 wkA1 = *(const f16x8*)&wh[4096 + wrow + 32];
    const f16x8 wvB0 = *(const f16x8*)&wh[8192 + wrow];
    const f16x8 wvB1 = *(const f16x8*)&wh[8192 + wrow + 32];

    // ======== per patch: proj -> barrier -> attention -> O over Xs[u] ========
    #pragma unroll
    for (int u = 0; u < PBLK; ++u) {
        // Q^T/K^T/V C-frags for all 4 token tiles (round-2-verified chains).
        f16x4 Qf[4], Kf[4], Vf[4];
        #pragma unroll
        for (int tt = 0; tt < 4; ++tt) {
            const int tok = tt * 16 + lr;
            const f16x8 xb0 = *(const f16x8*)&Xs[u][XS(tok, lg * 8)];
            const f16x8 xb1 = *(const f16x8*)&Xs[u][XS(tok, 32 + lg * 8)];
            f32x4 aq = MFMA32(wqA0, xb0, Z);
            aq = MFMA32(wqA1, xb1, aq);
            Qf[tt] = pack4(aq);                 // Q^T[d][tok=lr] (scaled, log2)
            f32x4 ak = MFMA32(wkA0, xb0, Z);
            ak = MFMA32(wkA1, xb1, ak);
            Kf[tt] = pack4(ak);                 // K^T C-frag == A-frag(K)
            f32x4 av = MFMA32(xb0, wvB0, Z);
            av = MFMA32(xb1, wvB1, av);
            Vf[tt] = pack4(av);                 // V C-frag == A-frag(V^T)
        }
        __syncthreads();   // Bu: ALL waves done reading Xs[u] -> O may overwrite

        #pragma unroll
        for (int tj = 0; tj < 4; ++tj) {
            // S^T[key=ti*16+lg*4+rg][q=tj*16+lr] (log2 domain)
            f32x4 s[4];
            #pragma unroll
            for (int ti = 0; ti < 4; ++ti)
                s[ti] = MFMA16(Kf[ti], Qf[tj], Z);

            // No max subtraction (r13-verified): exp2 directly off MFMA output.
            f16x4 pf[4];            // unnormalized P^T[key][q] as B-frags
            float ps[4];            // per-ti partial sums (tree)
            #pragma unroll
            for (int ti = 0; ti < 4; ++ti) {
                float e0 = __builtin_amdgcn_exp2f(s[ti][0]);
                float e1 = __builtin_amdgcn_exp2f(s[ti][1]);
                float e2 = __builtin_amdgcn_exp2f(s[ti][2]);
                float e3 = __builtin_amdgcn_exp2f(s[ti][3]);
                pf[ti][0] = (f16)e0;
                pf[ti][1] = (f16)e1;
                pf[ti][2] = (f16)e2;
                pf[ti][3] = (f16)e3;
                ps[ti] = (e0 + e1) + (e2 + e3);
            }
            float sum = (ps[0] + ps[1]) + (ps[2] + ps[3]);
            sum += __shfl_xor(sum, 16, 64);
            sum += __shfl_xor(sum, 32, 64);

            // PV MFMAs don't need sum -> overlap with the shfl reduce + rcp.
            f32x4 o = Z;
            #pragma unroll
            for (int ti = 0; ti < 4; ++ti)
                o = MFMA16(Vf[ti], pf[ti], o);  // O^T[d][q=tj*16+lr] unnormalized

            const float rs = __builtin_amdgcn_rcpf(sum);
            o[0] *= rs; o[1] *= rs; o[2] *= rs; o[3] *= rs;

            *(f16x4*)&Xs[u][XS(tj * 16 + lr, h * 16 + lg * 4)] = pack4(o);
        }
    }
    __syncthreads();   // Bf: all O writes done

    // ======== Phase 4: Y^T = Wp * O^T ; OB hoisted, ct-outer stores ========
    const f16* whp = wh + 3 * 4096;
    f16x4 wa[4][4];
    #pragma unroll
    for (int ct = 0; ct < 4; ++ct)
        #pragma unroll
        for (int dt = 0; dt < 4; ++dt)
            wa[ct][dt] = *(const f16x4*)&whp[(ct * 16 + lr) * 64 + dt * 16 + lg * 4];

    f16x4 OB[PBLK][4];   // O^T B-frags for the wave's own channel row, all u
    #pragma unroll
    for (int u = 0; u < PBLK; ++u)
        #pragma unroll
        for (int dt = 0; dt < 4; ++dt)
            OB[u][dt] = *(const f16x4*)&Xs[u][XS(chL, dt * 16 + lg * 4)];

    const int ch = b * 64 + chL;             // output channel (with batch)
    #pragma unroll
    for (int ct = 0; ct < 4; ++ct) {
        const int pi  = ct * 2 + (lg >> 1);  // cs=ct*16+lg*4+rg -> pi, pj=(lg&1)*4+rg
        const int pjh = lg & 1;
        const int hh  = r0 + pi;             // shared by all 4 patches (same ib)

        #pragma unroll
        for (int u = 0; u < PBLK; ++u) {
            f32x4 y = Z;
            #pragma unroll
            for (int dt = 0; dt < 4; ++dt)
                y = MFMA16(wa[ct][dt], OB[u][dt], y);
            // lane holds Y^T[cs=ct*16+lg*4+rg][tok=lr -> channel chL];
            // consecutive u at same ct -> adjacent 8B runs complete plane lines.
            if (USE_PLANES) {
                if (hh >= 0 && hh < 192) {
                    const int p = (pi >> 2) * 2 + pjh;
                    const size_t off = ((size_t)ch * 192 + hh) * 196 + 4 * (jb0 + u + pjh);
                    *(f16x4*)(planes + (size_t)p * PLELEM + off) = pack4(y);
                }
            } else {
                if (hh >= 0 && hh < 192) {
                    const float chc = (hh >= 2 && hh <= 189) ? 2.f : 1.f;
                    float* op = out + ((size_t)ch * 192 + hh) * 192;
                    const int c0u = c00 + 4 * u;
                    #pragma unroll
                    for (int rg = 0; rg < 4; ++rg) {
                        const int ww = c0u + pjh * 4 + rg;
                        if (ww >= 0 && ww < 192) {
                            const float cwc = (ww >= 2 && ww <= 189) ? 2.f : 1.f;
                            atomicAdd(op + ww, y[rg] / (chc * cwc + 1e-6f));
                        }
                    }
                }
            }
        }
    }
}

// ---- Pass B: vectorized fold of the 4 parity planes (4 outputs/thread) ----
// base elem offset = X*196 + (w0+2) with w0 = 0 mod 4 and 196 = 0 mod 4
// -> base = 2 mod 4 elems = 4B-aligned -> two f16x2 loads per plane.
__global__ __launch_bounds__(256) void fold_kernel(
    const f16* __restrict__ planes, float* __restrict__ out)
{
    const int idx4 = blockIdx.x * 256 + threadIdx.x;  // 0..2359295
    const int base4 = idx4 * 4;
    const int w0 = base4 % 192;
    const int t  = base4 / 192;
    const int h  = t % 192;
    const int bc = t / 192;
    const bool vlh = (h <= 189), vhh = (h >= 2);
    const size_t base = ((size_t)bc * 192 + h) * 196 + (w0 + 2);

    float v[4][4];   // [plane][elem]
    #pragma unroll
    for (int p = 0; p < 4; ++p) {
        const f16* pp = planes + (size_t)p * PLELEM + base;
        const f16x2 a = *(const f16x2*)pp;
        const f16x2 c = *(const f16x2*)(pp + 2);
        v[p][0] = (float)a[0]; v[p][1] = (float)a[1];
        v[p][2] = (float)c[0]; v[p][3] = (float)c[1];
    }

    f32x4 o;
    #pragma unroll
    for (int e = 0; e < 4; ++e) {
        const int w = w0 + e;
        const bool vlw = (w <= 189), vhw = (w >= 2);
        float s = 0.f;
        if (vlh && vlw) s += v[0][e];
        if (vlh && vhw) s += v[1][e];
        if (vhh && vlw) s += v[2][e];
        if (vhh && vhw) s += v[3][e];
        const float cnt = (float)(((int)vlh + (int)vhh) * ((int)vlw + (int)vhw));
        o[e] = s / (cnt + 1e-6f);
    }
    *(f32x4*)(out + base4) = o;
}

extern "C" void kernel_launch(void* const* d_in, const int* in_sizes, int n_in,
                              void* d_out, int out_size, void* d_ws, size_t ws_size,
                              hipStream_t stream)
{
    const float* x  = (const float*)d_in[0];
    const float* wq = (const float*)d_in[1];
    const float* wk = (const float*)d_in[2];
    const float* wv = (const float*)d_in[3];
    const float* wp = (const float*)d_in[4];
    float* out = (float*)d_out;
    f16* wh = (f16*)d_ws;

    wcvt_kernel<<<64, 256, 0, stream>>>(wq, wk, wv, wp, wh);

    if (ws_size >= WS_NEED) {
        f16* planes = (f16*)((char*)d_ws + 32768);
        patch_attn_kernel<true><<<NBLK, 256, 0, stream>>>(x, wh, planes, out);
        fold_kernel<<<9216, 256, 0, stream>>>(planes, out);   // 4 outputs/thread
    } else {
        hipMemsetAsync(d_out, 0, (size_t)out_size * sizeof(float), stream);
        patch_attn_kernel<false><<<NBLK, 256, 0, stream>>>(x, wh, nullptr, out);
    }
}

// Round 21
// 110.842 us; speedup vs baseline: 1.2205x; 1.0048x over previous
//
#include <hip/hip_runtime.h>

// LocalRefinedAttention round 21 = round 19 + CORRECTED deferred normalization.
// Round 20 post-mortem: FAILED (absmax 11.3) -- softmax sums are PER-HEAD;
// a single per-q scale can't commute through the Wp GEMM (contraction spans
// all 4 heads), and Ssum[u][q] was racy across head-waves. Fix: per-(head,q)
// reciprocal sums in Ssum[u][4][64] (written by lg==0 after the shfl reduce,
// which is now OFF the critical path -- PV uses unnormalized pf), and phase 4
// scales OB[u][dt] (head dt's B-frag at the lane's q=chL) in f32 BEFORE the
// Wp MFMA. O stored unnormalized in f16 (magnitude <= few K, safe). PV and
// phase-4 MFMA chains stay 2x2-split.
//
// B=4, C=64, H=W=192, PS=8, STRIDE=4, PAD=2, NHEADS=4, head_dim=16.
// token t = channel; feature/spatial s = pi*8+pj; h = 4*ib+pi-2, w = 4*jb+pj-2.
// Parity planes: p = (pi>=4)*2 + (pj>=4); plane[p][b][ch][h][w2=196] at w2=w+2.
// Each (pixel, p) has exactly one writing patch -> no atomics, no memset.

typedef _Float16 f16;
typedef _Float16 f16x2 __attribute__((ext_vector_type(2)));
typedef _Float16 f16x4 __attribute__((ext_vector_type(4)));
typedef _Float16 f16x8 __attribute__((ext_vector_type(8)));
typedef float    f32x4 __attribute__((ext_vector_type(4)));

#define NHP 48
#define LPB (NHP * NHP)          // 2304
#define NPATCH (4 * LPB)         // 9216
#define PBLK 4                   // patches per block (same ib, jb0..jb0+3)
#define NBLK (NPATCH / PBLK)     // 2304 blocks
#define PLELEM (256 * 192 * 196) // f16 elements per parity plane
#define WS_NEED (32768ull + 4ull * PLELEM * 2ull)

#define MFMA32(A, B, C) __builtin_amdgcn_mfma_f32_16x16x32_f16((A), (B), (C), 0, 0, 0)
#define MFMA16(A, B, C) __builtin_amdgcn_mfma_f32_16x16x16f16((A), (B), (C), 0, 0, 0)

// XOR-swizzled LDS index: token-major pitch 64 f16; flips f16-index bits 3..5
// by (tok&7). Same swizzle on write and read sides.
static __device__ __forceinline__ int XS(int tok, int f) {
    return tok * 64 + (f ^ ((tok & 7) << 3));
}

static __device__ __forceinline__ f16x4 pack4(f32x4 a) {
    f16x4 r;
    r[0] = (f16)a[0]; r[1] = (f16)a[1]; r[2] = (f16)a[2]; r[3] = (f16)a[3];
    return r;
}

// ---- weights fp32 -> f16 row-major; SCALE*log2(e) folded into Wq ----
__global__ __launch_bounds__(256) void wcvt_kernel(
    const float* __restrict__ wq, const float* __restrict__ wk,
    const float* __restrict__ wv, const float* __restrict__ wp,
    f16* __restrict__ wh)
{
    const int idx = blockIdx.x * 256 + threadIdx.x;   // 0..16383
    const int m = idx >> 12;
    const int r = idx & 4095;
    const float* src = (m == 0) ? wq : (m == 1) ? wk : (m == 2) ? wv : wp;
    const float s = (m == 0) ? 0.36067376022224085f : 1.0f;  // 0.25 * log2(e)
    wh[idx] = (f16)(src[r] * s);
}

template <bool USE_PLANES>
__global__ __launch_bounds__(256, 4) void patch_attn_kernel(
    const float* __restrict__ x, const f16* __restrict__ wh,
    f16* __restrict__ planes, float* __restrict__ out)
{
    // Xs[u]: X tokens (swizzled pitch 64) -> after per-patch barrier, reused
    // as UNNORMALIZED O. Ssum[u][head][q] = 1/sum (written by lg==0 lanes).
    __shared__ f16 Xs[PBLK][64 * 64];        // 32 KB
    __shared__ float Ssum[PBLK][4][64];      // 4 KB

    const int tid  = threadIdx.x;
    const int wv_  = tid >> 6;
    const int lane = tid & 63;
    const int lr   = lane & 15;
    const int lg   = lane >> 4;
    const int chL  = wv_ * 16 + lr;          // this thread's token/channel row

    // XCD-bijective swizzle; consecutive same-XCD blocks = consecutive
    // 4-patch groups (HW dispatch order -> jb-adjacent concurrent blocks).
    const int n    = blockIdx.x;
    const int qb   = (n & 7) * (NBLK / 8) + (n >> 3);
    const int pid0 = qb * PBLK;
    const int b    = pid0 / LPB;
    const int rem  = pid0 - b * LPB;
    const int ib   = rem / NHP;
    const int jb0  = rem - ib * NHP;         // block patches: jb0..jb0+3
    const int r0   = ib * 4 - 2;             // shared rows (same ib for all 4)
    const int c00  = jb0 * 4 - 2;            // patch u starts at c00 + 4u

    const f32x4 Z = (f32x4){0.f, 0.f, 0.f, 0.f};

    // ======== X global loads (deduped across the 4 patches) ========
    float2 xr[2][10];
    {
        const float* xb = x + ((size_t)(b * 64 + chL) * 192) * 192;
        #pragma unroll
        for (int kt = 0; kt < 2; ++kt) {
            const int rr = r0 + kt * 4 + lg;
            const int rc = (rr >= 0 && rr < 192) ? rr : 0;
            const float* src = xb + (size_t)rc * 192;
            #pragma unroll
            for (int j = 0; j < 10; ++j) {
                int cc = c00 + 2 * j;
                cc = (cc < 0) ? 0 : ((cc > 190) ? 190 : cc);
                xr[kt][j] = *(const float2*)(src + cc);
            }
        }
    }

    // ---- convert once with shared masks ----
    f16x2 ht[2][10];
    #pragma unroll
    for (int kt = 0; kt < 2; ++kt) {
        const int rr = r0 + kt * 4 + lg;
        const bool rko = (rr >= 0) && (rr < 192);
        #pragma unroll
        for (int j = 0; j < 10; ++j) {
            const int cc = c00 + 2 * j;
            const bool ok = rko && (cc >= 0) && (cc <= 190);
            ht[kt][j][0] = ok ? (f16)xr[kt][j].x : (f16)0.f;
            ht[kt][j][1] = ok ? (f16)xr[kt][j].y : (f16)0.f;
        }
    }

    // ---- stage X to LDS (swizzled) ----
    #pragma unroll
    for (int u = 0; u < PBLK; ++u)
        #pragma unroll
        for (int kt = 0; kt < 2; ++kt) {
            f16x8 v;
            #pragma unroll
            for (int j = 0; j < 4; ++j) {
                v[2 * j]     = ht[kt][2 * u + j][0];
                v[2 * j + 1] = ht[kt][2 * u + j][1];
            }
            *(f16x8*)&Xs[u][XS(chL, kt * 32 + lg * 8)] = v;
        }
    __syncthreads();   // B0: X staged for all 4 patches

    // ======== wave = head h: own-head weight fragments (once) ========
    const int h = wv_;
    const int wrow = (h * 16 + lr) * 64 + lg * 8;
    const f16x8 wqA0 = *(const f16x8*)&wh[wrow];
    const f16x8 wqA1 = *(const f16x8*)&wh[wrow + 32];
    const f16x8 wkA0 = *(const f16x8*)&wh[4096 + wrow];
    const f16x8 wkA1 = *(const f16x8*)&wh[4096 + wrow + 32];
    const f16x8 wvB0 = *(const f16x8*)&wh[8192 + wrow];
    const f16x8 wvB1 = *(const f16x8*)&wh[8192 + wrow + 32];

    // ======== per patch: proj -> barrier -> attention -> O over Xs[u] ========
    #pragma unroll
    for (int u = 0; u < PBLK; ++u) {
        // Q^T/K^T/V C-frags for all 4 token tiles (round-2-verified chains).
        f16x4 Qf[4], Kf[4], Vf[4];
        #pragma unroll
        for (int tt = 0; tt < 4; ++tt) {
            const int tok = tt * 16 + lr;
            const f16x8 xb0 = *(const f16x8*)&Xs[u][XS(tok, lg * 8)];
            const f16x8 xb1 = *(const f16x8*)&Xs[u][XS(tok, 32 + lg * 8)];
            f32x4 aq = MFMA32(wqA0, xb0, Z);
            aq = MFMA32(wqA1, xb1, aq);
            Qf[tt] = pack4(aq);                 // Q^T[d][tok=lr] (scaled, log2)
            f32x4 ak = MFMA32(wkA0, xb0, Z);
            ak = MFMA32(wkA1, xb1, ak);
            Kf[tt] = pack4(ak);                 // K^T C-frag == A-frag(K)
            f32x4 av = MFMA32(xb0, wvB0, Z);
            av = MFMA32(xb1, wvB1, av);
            Vf[tt] = pack4(av);                 // V C-frag == A-frag(V^T)
        }
        __syncthreads();   // Bu: ALL waves done reading Xs[u] -> O may overwrite

        #pragma unroll
        for (int tj = 0; tj < 4; ++tj) {
            // S^T[key=ti*16+lg*4+rg][q=tj*16+lr] (log2 domain)
            f32x4 s[4];
            #pragma unroll
            for (int ti = 0; ti < 4; ++ti)
                s[ti] = MFMA16(Kf[ti], Qf[tj], Z);

            // No max subtraction (r13-verified): exp2 directly off MFMA output.
            f16x4 pf[4];            // unnormalized P^T[key][q] as B-frags
            float ps[4];            // per-ti partial sums
            #pragma unroll
            for (int ti = 0; ti < 4; ++ti) {
                float e0 = __builtin_amdgcn_exp2f(s[ti][0]);
                float e1 = __builtin_amdgcn_exp2f(s[ti][1]);
                float e2 = __builtin_amdgcn_exp2f(s[ti][2]);
                float e3 = __builtin_amdgcn_exp2f(s[ti][3]);
                pf[ti][0] = (f16)e0;
                pf[ti][1] = (f16)e1;
                pf[ti][2] = (f16)e2;
                pf[ti][3] = (f16)e3;
                ps[ti] = (e0 + e1) + (e2 + e3);
            }
            // Full per-head sum; OFF the critical path (PV uses pf directly).
            float sum = (ps[0] + ps[1]) + (ps[2] + ps[3]);
            sum += __shfl_xor(sum, 16, 64);
            sum += __shfl_xor(sum, 32, 64);
            if (lg == 0)
                Ssum[u][h][tj * 16 + lr] = __builtin_amdgcn_rcpf(sum);

            // PV: 2x2 split + add; result UNNORMALIZED.
            f32x4 o01 = MFMA16(Vf[0], pf[0], Z);
            o01 = MFMA16(Vf[1], pf[1], o01);
            f32x4 o23 = MFMA16(Vf[2], pf[2], Z);
            o23 = MFMA16(Vf[3], pf[3], o23);
            const f32x4 o = o01 + o23;          // O^T[d][q] unnormalized

            *(f16x4*)&Xs[u][XS(tj * 16 + lr, h * 16 + lg * 4)] = pack4(o);
        }
    }
    __syncthreads();   // Bf: all O + rs writes visible

    // ======== Phase 4: Y^T = Wp * O^T ; per-head deferred normalization ====
    const f16* whp = wh + 3 * 4096;
    f16x4 wa[4][4];
    #pragma unroll
    for (int ct = 0; ct < 4; ++ct)
        #pragma unroll
        for (int dt = 0; dt < 4; ++dt)
            wa[ct][dt] = *(const f16x4*)&whp[(ct * 16 + lr) * 64 + dt * 16 + lg * 4];

    // O^T B-frags for the wave's own token q = chL; scale head dt's frag by
    // rs[u][dt] (all of a lane's B-frag values belong to q = chL -> legal
    // per-lane scalar multiply, in f32 for precision).
    f16x4 OB[PBLK][4];
    #pragma unroll
    for (int u = 0; u < PBLK; ++u)
        #pragma unroll
        for (int dt = 0; dt < 4; ++dt) {
            const float rs = Ssum[u][dt][chL];   // 4-lane broadcast (free)
            const f16x4 ob = *(const f16x4*)&Xs[u][XS(chL, dt * 16 + lg * 4)];
            f16x4 sc;
            sc[0] = (f16)((float)ob[0] * rs);
            sc[1] = (f16)((float)ob[1] * rs);
            sc[2] = (f16)((float)ob[2] * rs);
            sc[3] = (f16)((float)ob[3] * rs);
            OB[u][dt] = sc;
        }

    const int ch = b * 64 + chL;             // output channel (with batch)
    #pragma unroll
    for (int ct = 0; ct < 4; ++ct) {
        const int pi  = ct * 2 + (lg >> 1);  // cs=ct*16+lg*4+rg -> pi, pj=(lg&1)*4+rg
        const int pjh = lg & 1;
        const int hh  = r0 + pi;             // shared by all 4 patches (same ib)

        #pragma unroll
        for (int u = 0; u < PBLK; ++u) {
            f32x4 y01 = MFMA16(wa[ct][0], OB[u][0], Z);
            y01 = MFMA16(wa[ct][1], OB[u][1], y01);
            f32x4 y23 = MFMA16(wa[ct][2], OB[u][2], Z);
            y23 = MFMA16(wa[ct][3], OB[u][3], y23);
            const f32x4 y = y01 + y23;
            // lane holds Y^T[cs=ct*16+lg*4+rg][tok=lr -> channel chL];
            // consecutive u at same ct -> adjacent 8B runs complete plane lines.
            if (USE_PLANES) {
                if (hh >= 0 && hh < 192) {
                    const int p = (pi >> 2) * 2 + pjh;
                    const size_t off = ((size_t)ch * 192 + hh) * 196 + 4 * (jb0 + u + pjh);
                    *(f16x4*)(planes + (size_t)p * PLELEM + off) = pack4(y);
                }
            } else {
                if (hh >= 0 && hh < 192) {
                    const float chc = (hh >= 2 && hh <= 189) ? 2.f : 1.f;
                    float* op = out + ((size_t)ch * 192 + hh) * 192;
                    const int c0u = c00 + 4 * u;
                    #pragma unroll
                    for (int rg = 0; rg < 4; ++rg) {
                        const int ww = c0u + pjh * 4 + rg;
                        if (ww >= 0 && ww < 192) {
                            const float cwc = (ww >= 2 && ww <= 189) ? 2.f : 1.f;
                            atomicAdd(op + ww, y[rg] / (chc * cwc + 1e-6f));
                        }
                    }
                }
            }
        }
    }
}

// ---- Pass B: vectorized fold of the 4 parity planes (4 outputs/thread) ----
// base elem offset = X*196 + (w0+2) with w0 = 0 mod 4 and 196 = 0 mod 4
// -> base = 2 mod 4 elems = 4B-aligned -> two f16x2 loads per plane.
__global__ __launch_bounds__(256) void fold_kernel(
    const f16* __restrict__ planes, float* __restrict__ out)
{
    const int idx4 = blockIdx.x * 256 + threadIdx.x;  // 0..2359295
    const int base4 = idx4 * 4;
    const int w0 = base4 % 192;
    const int t  = base4 / 192;
    const int h  = t % 192;
    const int bc = t / 192;
    const bool vlh = (h <= 189), vhh = (h >= 2);
    const size_t base = ((size_t)bc * 192 + h) * 196 + (w0 + 2);

    float v[4][4];   // [plane][elem]
    #pragma unroll
    for (int p = 0; p < 4; ++p) {
        const f16* pp = planes + (size_t)p * PLELEM + base;
        const f16x2 a = *(const f16x2*)pp;
        const f16x2 c = *(const f16x2*)(pp + 2);
        v[p][0] = (float)a[0]; v[p][1] = (float)a[1];
        v[p][2] = (float)c[0]; v[p][3] = (float)c[1];
    }

    f32x4 o;
    #pragma unroll
    for (int e = 0; e < 4; ++e) {
        const int w = w0 + e;
        const bool vlw = (w <= 189), vhw = (w >= 2);
        float s = 0.f;
        if (vlh && vlw) s += v[0][e];
        if (vlh && vhw) s += v[1][e];
        if (vhh && vlw) s += v[2][e];
        if (vhh && vhw) s += v[3][e];
        const float cnt = (float)(((int)vlh + (int)vhh) * ((int)vlw + (int)vhw));
        o[e] = s / (cnt + 1e-6f);
    }
    *(f32x4*)(out + base4) = o;
}

extern "C" void kernel_launch(void* const* d_in, const int* in_sizes, int n_in,
                              void* d_out, int out_size, void* d_ws, size_t ws_size,
                              hipStream_t stream)
{
    const float* x  = (const float*)d_in[0];
    const float* wq = (const float*)d_in[1];
    const float* wk = (const float*)d_in[2];
    const float* wv = (const float*)d_in[3];
    const float* wp = (const float*)d_in[4];
    float* out = (float*)d_out;
    f16* wh = (f16*)d_ws;

    wcvt_kernel<<<64, 256, 0, stream>>>(wq, wk, wv, wp, wh);

    if (ws_size >= WS_NEED) {
        f16* planes = (f16*)((char*)d_ws + 32768);
        patch_attn_kernel<true><<<NBLK, 256, 0, stream>>>(x, wh, planes, out);
        fold_kernel<<<9216, 256, 0, stream>>>(planes, out);   // 4 outputs/thread
    } else {
        hipMemsetAsync(d_out, 0, (size_t)out_size * sizeof(float), stream);
        patch_attn_kernel<false><<<NBLK, 256, 0, stream>>>(x, wh, nullptr, out);
    }
}